// Round 1
// baseline (245.381 us; speedup 1.0000x reference)
//
#include <hip/hip_runtime.h>
#include <math.h>

#define N_NODES 60000
#define N_EDGES 240000
#define F_INQ 10
#define G_DIM 512
#define NB_SCAN ((N_NODES + 255) / 256)   // 235
#define NB_EDGE ((N_EDGES + 255) / 256)   // 938

// ===========================================================================
// CSR build (unchanged): deg -> block scan -> block-sum scan -> fill with
// reordered edge records. After k_fill: global end(i) = rs[i]+bsum[i>>8].
// ===========================================================================
__global__ __launch_bounds__(256) void k_deg(
    const int* __restrict__ ei, int* __restrict__ rs)
{
    int e = blockIdx.x * 256 + threadIdx.x;
    if (e < N_EDGES) atomicAdd(&rs[ei[e]], 1);
}

__global__ __launch_bounds__(256) void k_scan_a(
    int* __restrict__ rs, int* __restrict__ bsum)
{
    __shared__ int s[256];
    int i = blockIdx.x * 256 + threadIdx.x;
    int v = (i < N_NODES) ? rs[i] : 0;
    s[threadIdx.x] = v;
    __syncthreads();
    for (int off = 1; off < 256; off <<= 1) {
        int t = (threadIdx.x >= off) ? s[threadIdx.x - off] : 0;
        __syncthreads();
        s[threadIdx.x] += t;
        __syncthreads();
    }
    if (i < N_NODES) rs[i] = s[threadIdx.x] - v;  // block-local exclusive
    if (threadIdx.x == 255) bsum[blockIdx.x] = s[255];
}

__global__ __launch_bounds__(256) void k_scan_b(int* __restrict__ bsum)
{
    __shared__ int s[256];
    int v = (threadIdx.x < NB_SCAN) ? bsum[threadIdx.x] : 0;
    s[threadIdx.x] = v;
    __syncthreads();
    for (int off = 1; off < 256; off <<= 1) {
        int t = (threadIdx.x >= off) ? s[threadIdx.x - off] : 0;
        __syncthreads();
        s[threadIdx.x] += t;
        __syncthreads();
    }
    if (threadIdx.x < NB_SCAN) bsum[threadIdx.x] = s[threadIdx.x] - v;  // exclusive
}

__global__ __launch_bounds__(256) void k_fill(
    const int* __restrict__ ei, const float* __restrict__ a_vals,
    const float* __restrict__ efeat,
    int* __restrict__ rs, const int* __restrict__ bsum,
    int* __restrict__ ecol, float4* __restrict__ edata)
{
    int e = blockIdx.x * 256 + threadIdx.x;
    if (e >= N_EDGES) return;
    int row = ei[e];
    int slot = atomicAdd(&rs[row], 1) + bsum[row >> 8];
    ecol[slot] = ei[N_EDGES + e];
    edata[slot] = make_float4(a_vals[e], efeat[e * 3], efeat[e * 3 + 1], efeat[e * 3 + 2]);
}

// ---------------------------------------------------------------------------
// K_layer1: FUSED edge-reduction + node transform, layer 1.
// Block = 16 node-groups x 16 lanes; node = blockIdx*16+grp (3750 blocks
// exact). Phase 1 (lanes f<10): CSR reduction into LDS pq[grp][50]
// ([P0|P1|P2|P3|Q], 10 each) + stash x_self into xs[grp][10].
// Phase 2 (all lanes, o = lane): per-node transform straight from LDS:
//   c1 = relu(P0@be1 + sum_s Ps@We1_s + x_self@root1 + bias1)
//   g1 = relu(Q@Wg1 + b_gcn1)
// Output interleaved g1c1[n,32] = [g1(16)|c1(16)]. PQ1 never hits global.
// ---------------------------------------------------------------------------
__global__ __launch_bounds__(256) void k_layer1(
    const float* __restrict__ x,
    const int* __restrict__ rs, const int* __restrict__ bsum,
    const int* __restrict__ ecol, const float4* __restrict__ edata,
    const float* __restrict__ Wg1,   // [10,16]
    const float* __restrict__ We1,   // [3,160]
    const float* __restrict__ be1,   // [160]
    const float* __restrict__ root1, // [10,16]
    const float* __restrict__ bias1, // [16]
    const float* __restrict__ bg1,   // [16]
    float* __restrict__ g1c1)
{
    // w: wg(160)|w0|w1|w2(@160,320,480)|bm=be1(@640)|rt=root1(@800)|bias1(@960)|bg1(@976)
    __shared__ float w[6 * 160 + 32];
    __shared__ float pq[16][50];
    __shared__ float xs[16][10];
    for (int t = threadIdx.x; t < 6 * 160 + 32; t += 256) {
        float v;
        if (t < 960) {
            int slot = t / 160, r = t - slot * 160;
            if (slot == 0)      v = Wg1[r];
            else if (slot <= 3) v = We1[(slot - 1) * 160 + r];
            else if (slot == 4) v = be1[r];
            else                v = root1[r];
        } else if (t < 976) v = bias1[t - 960];
        else                v = bg1[t - 976];
        w[t] = v;
    }
    int grp = threadIdx.x >> 4, f = threadIdx.x & 15;
    int node = blockIdx.x * 16 + grp;
    if (f < F_INQ) {
        int end = rs[node] + bsum[node >> 8];
        int start = (node == 0) ? 0 : (rs[node - 1] + bsum[(node - 1) >> 8]);
        float p0 = 0.f, p1 = 0.f, p2 = 0.f, p3 = 0.f, q = 0.f;
        for (int k = start; k < end; ++k) {
            int col = ecol[k];
            float4 ed = edata[k];
            float xv = x[col * F_INQ + f];
            p0 += xv;
            p1 += ed.y * xv;
            p2 += ed.z * xv;
            p3 += ed.w * xv;
            q  += ed.x * xv;
        }
        pq[grp][f]      = p0;
        pq[grp][10 + f] = p1;
        pq[grp][20 + f] = p2;
        pq[grp][30 + f] = p3;
        pq[grp][40 + f] = q;
        xs[grp][f] = x[node * F_INQ + f];
    }
    __syncthreads();
    int o = f;
    float ac = w[960 + o], ag = w[976 + o];
#pragma unroll
    for (int ff = 0; ff < 10; ++ff) {
        ac += pq[grp][ff]      * w[640 + ff * 16 + o]
            + pq[grp][10 + ff] * w[160 + ff * 16 + o]
            + pq[grp][20 + ff] * w[320 + ff * 16 + o]
            + pq[grp][30 + ff] * w[480 + ff * 16 + o]
            + xs[grp][ff]      * w[800 + ff * 16 + o];
        ag += pq[grp][40 + ff] * w[ff * 16 + o];
    }
    g1c1[node * 32 + o]      = ag > 0.f ? ag : 0.f;
    g1c1[node * 32 + 16 + o] = ac > 0.f ? ac : 0.f;
}

// ---------------------------------------------------------------------------
// K_layer2: FUSED edge-reduction + node transform + per-graph pooling.
// Block = 16 node-groups x 16 lanes. Phase 1: CSR reduction into LDS
// pq[grp][80] ([P0..P3 over c1 | Q over a*g1], 16 each) + c1_self + seg.
// Phase 2 (thread = (n, o<32), two passes of 8 nodes):
//   c2 = relu(P0@be2 + sum_s Ps@We2_s + c1_self@root2 + bias2)
//   g2 = relu(Q@Wg2 + b_gcn2)   -> val[n][64] = [g2(32)|c2(32)]
// Phase 3 (lanes 0..63): run-detect on sorted seg within block, one
// atomicAdd per (graph-run, channel) into pool[G,64]. g2c2 never exists.
// ---------------------------------------------------------------------------
__global__ __launch_bounds__(256) void k_layer2(
    const float* __restrict__ g1c1,
    const int* __restrict__ rs, const int* __restrict__ bsum,
    const int* __restrict__ ecol, const float4* __restrict__ edata,
    const int* __restrict__ seg,
    const float* __restrict__ Wg2,   // [16,32]
    const float* __restrict__ We2,   // [3,512]
    const float* __restrict__ be2,   // [512]
    const float* __restrict__ root2, // [16,32]
    const float* __restrict__ bias2, // [32]
    const float* __restrict__ bg2,   // [32]
    float* __restrict__ pool)
{
    // w: wg(512)|w0|w1|w2(@512,1024,1536)|bm=be2(@2048)|rt=root2(@2560)|bias2(@3072)|bg2(@3104)
    __shared__ float w[6 * 512 + 64];
    __shared__ float pq[16][80];
    __shared__ float cs[16][16];
    __shared__ float val[16][64];
    __shared__ int   sseg[16];
    for (int t = threadIdx.x; t < 6 * 512 + 64; t += 256) {
        float v;
        if (t < 3072) {
            int slot = t >> 9, r = t & 511;
            if (slot == 0)      v = Wg2[r];
            else if (slot <= 3) v = We2[(slot - 1) * 512 + r];
            else if (slot == 4) v = be2[r];
            else                v = root2[r];
        } else if (t < 3104) v = bias2[t - 3072];
        else                 v = bg2[t - 3104];
        w[t] = v;
    }
    int grp = threadIdx.x >> 4, f = threadIdx.x & 15;
    int node = blockIdx.x * 16 + grp;
    {
        int end = rs[node] + bsum[node >> 8];
        int start = (node == 0) ? 0 : (rs[node - 1] + bsum[(node - 1) >> 8]);
        float p0 = 0.f, p1 = 0.f, p2 = 0.f, p3 = 0.f, q = 0.f;
        for (int k = start; k < end; ++k) {
            int col = ecol[k];
            float4 ed = edata[k];
            float gv = g1c1[col * 32 + f];
            float cv = g1c1[col * 32 + 16 + f];
            p0 += cv;
            p1 += ed.y * cv;
            p2 += ed.z * cv;
            p3 += ed.w * cv;
            q  += ed.x * gv;
        }
        pq[grp][f]      = p0;
        pq[grp][16 + f] = p1;
        pq[grp][32 + f] = p2;
        pq[grp][48 + f] = p3;
        pq[grp][64 + f] = q;
        cs[grp][f] = g1c1[node * 32 + 16 + f];
        if (f == 0) sseg[grp] = seg[node];
    }
    __syncthreads();
    int o = threadIdx.x & 31;
    int nh = threadIdx.x >> 5;           // 0..7
#pragma unroll
    for (int pass = 0; pass < 2; ++pass) {
        int n = pass * 8 + nh;
        float ac = w[3072 + o], ag = w[3104 + o];
#pragma unroll
        for (int ff = 0; ff < 16; ++ff) {
            ac += pq[n][ff]      * w[2048 + ff * 32 + o]
                + pq[n][16 + ff] * w[512  + ff * 32 + o]
                + pq[n][32 + ff] * w[1024 + ff * 32 + o]
                + pq[n][48 + ff] * w[1536 + ff * 32 + o]
                + cs[n][ff]      * w[2560 + ff * 32 + o];
            ag += pq[n][64 + ff] * w[ff * 32 + o];
        }
        val[n][o]      = ag > 0.f ? ag : 0.f;   // g2
        val[n][32 + o] = ac > 0.f ? ac : 0.f;   // c2
    }
    __syncthreads();
    if (threadIdx.x < 64) {
        int c = threadIdx.x;
        float acc = val[0][c];
        int curg = sseg[0];
        for (int n = 1; n < 16; ++n) {
            int gn = sseg[n];
            if (gn != curg) {
                atomicAdd(&pool[curg * 64 + c], acc);
                acc = 0.f;
                curg = gn;
            }
            acc += val[n][c];
        }
        atomicAdd(&pool[curg * 64 + c], acc);
    }
}

// ---------------------------------------------------------------------------
// K_head: 4 graphs per block (64 threads each = one wave per graph).
// Reads pool[G,64] (131 KB total) -> fused MLP head -> sigmoid.
// ---------------------------------------------------------------------------
__global__ __launch_bounds__(256) void k_head(
    const float* __restrict__ pool,
    const float* __restrict__ Wd1, const float* __restrict__ bd1,
    const float* __restrict__ Wd2, const float* __restrict__ bd2,
    const float* __restrict__ Wo,  const float* __restrict__ bo,
    float* __restrict__ out)
{
    __shared__ float pl[4][64];
    __shared__ float h1s[4][16];
    __shared__ float h2s[4][8];
    int q = threadIdx.x >> 6, t = threadIdx.x & 63;
    int g = blockIdx.x * 4 + q;
    pl[q][t] = pool[g * 64 + t];
    __syncthreads();
    if (t < 16) {
        float a = bd1[t];
        for (int k = 0; k < 64; ++k) a += pl[q][k] * Wd1[k * 16 + t];
        h1s[q][t] = a > 0.f ? a : 0.f;
    }
    __syncthreads();
    if (t < 8) {
        float a = bd2[t];
        for (int k = 0; k < 16; ++k) a += h1s[q][k] * Wd2[k * 8 + t];
        h2s[q][t] = a > 0.f ? a : 0.f;
    }
    __syncthreads();
    if (t == 0) {
        float a = bo[0];
        for (int k = 0; k < 8; ++k) a += h2s[q][k] * Wo[k];
        out[g] = 1.f / (1.f + expf(-a));
    }
}

// ---------------------------------------------------------------------------
// Workspace layout (~12.9 MB):
//   edata E*float4 | g1c1 N*32 (floats) | rs[N] | pool[G*64] | bsum[256] | ecol[E]
//   (rs and pool contiguous -> single memset zeroes both)
// ---------------------------------------------------------------------------
extern "C" void kernel_launch(void* const* d_in, const int* in_sizes, int n_in,
                              void* d_out, int out_size, void* d_ws, size_t ws_size,
                              hipStream_t stream)
{
    const float* x      = (const float*)d_in[0];
    const float* a_vals = (const float*)d_in[1];
    const float* efeat  = (const float*)d_in[2];
    const int*   ei     = (const int*)d_in[3];
    const int*   seg    = (const int*)d_in[4];
    const float* Wg1    = (const float*)d_in[5];
    const float* bg1    = (const float*)d_in[6];
    const float* Wg2    = (const float*)d_in[7];
    const float* bg2    = (const float*)d_in[8];
    const float* We1    = (const float*)d_in[9];
    const float* be1    = (const float*)d_in[10];
    const float* root1  = (const float*)d_in[11];
    const float* bias1  = (const float*)d_in[12];
    const float* We2    = (const float*)d_in[13];
    const float* be2    = (const float*)d_in[14];
    const float* root2  = (const float*)d_in[15];
    const float* bias2  = (const float*)d_in[16];
    const float* Wd1    = (const float*)d_in[17];
    const float* bd1    = (const float*)d_in[18];
    const float* Wd2    = (const float*)d_in[19];
    const float* bd2    = (const float*)d_in[20];
    const float* Wo     = (const float*)d_in[21];
    const float* bo     = (const float*)d_in[22];

    float4* edata = (float4*)d_ws;
    float*  g1c1 = (float*)(edata + N_EDGES);
    int*    rs   = (int*)(g1c1 + (size_t)N_NODES * 32);
    float*  pool = (float*)(rs + N_NODES);
    int*    bsum = (int*)(pool + (size_t)G_DIM * 64);
    int*    ecol = bsum + 256;
    float*  out  = (float*)d_out;

    // zero rs (degree counters) and pool (atomic accumulators) in one shot
    hipMemsetAsync(rs, 0, sizeof(int) * (N_NODES + G_DIM * 64), stream);

    // CSR build
    k_deg    <<<NB_EDGE, 256, 0, stream>>>(ei, rs);
    k_scan_a <<<NB_SCAN, 256, 0, stream>>>(rs, bsum);
    k_scan_b <<<1, 256, 0, stream>>>(bsum);
    k_fill   <<<NB_EDGE, 256, 0, stream>>>(ei, a_vals, efeat, rs, bsum, ecol, edata);

    // Layer 1 fused (edge reduce + transform), layer 2 fused (+ pooling)
    k_layer1<<<N_NODES / 16, 256, 0, stream>>>(x, rs, bsum, ecol, edata,
                                               Wg1, We1, be1, root1, bias1, bg1, g1c1);
    k_layer2<<<N_NODES / 16, 256, 0, stream>>>(g1c1, rs, bsum, ecol, edata, seg,
                                               Wg2, We2, be2, root2, bias2, bg2, pool);

    // MLP head
    k_head<<<G_DIM / 4, 256, 0, stream>>>(pool, Wd1, bd1, Wd2, bd2, Wo, bo, out);
}

// Round 2
// 240.057 us; speedup vs baseline: 1.0222x; 1.0222x over previous
//
#include <hip/hip_runtime.h>
#include <math.h>

#define N_NODES 60000
#define N_EDGES 240000
#define F_INQ 10
#define G_DIM 512
#define NB_SCAN ((N_NODES + 255) / 256)   // 235
#define NB_EDGE ((N_EDGES + 255) / 256)   // 938
#define N_CHUNK (N_NODES / 16)            // 3750 16-node chunks

// ===========================================================================
// CSR build: deg -> block scan -> block-sum scan -> fill with reordered edge
// records. After k_fill: global end(i) = rs[i]+bsum[i>>8].
// ===========================================================================
__global__ __launch_bounds__(256) void k_deg(
    const int* __restrict__ ei, int* __restrict__ rs)
{
    int e = blockIdx.x * 256 + threadIdx.x;
    if (e < N_EDGES) atomicAdd(&rs[ei[e]], 1);
}

__global__ __launch_bounds__(256) void k_scan_a(
    int* __restrict__ rs, int* __restrict__ bsum)
{
    __shared__ int s[256];
    int i = blockIdx.x * 256 + threadIdx.x;
    int v = (i < N_NODES) ? rs[i] : 0;
    s[threadIdx.x] = v;
    __syncthreads();
    for (int off = 1; off < 256; off <<= 1) {
        int t = (threadIdx.x >= off) ? s[threadIdx.x - off] : 0;
        __syncthreads();
        s[threadIdx.x] += t;
        __syncthreads();
    }
    if (i < N_NODES) rs[i] = s[threadIdx.x] - v;  // block-local exclusive
    if (threadIdx.x == 255) bsum[blockIdx.x] = s[255];
}

__global__ __launch_bounds__(256) void k_scan_b(int* __restrict__ bsum)
{
    __shared__ int s[256];
    int v = (threadIdx.x < NB_SCAN) ? bsum[threadIdx.x] : 0;
    s[threadIdx.x] = v;
    __syncthreads();
    for (int off = 1; off < 256; off <<= 1) {
        int t = (threadIdx.x >= off) ? s[threadIdx.x - off] : 0;
        __syncthreads();
        s[threadIdx.x] += t;
        __syncthreads();
    }
    if (threadIdx.x < NB_SCAN) bsum[threadIdx.x] = s[threadIdx.x] - v;  // exclusive
}

__global__ __launch_bounds__(256) void k_fill(
    const int* __restrict__ ei, const float* __restrict__ a_vals,
    const float* __restrict__ efeat,
    int* __restrict__ rs, const int* __restrict__ bsum,
    int* __restrict__ ecol, float4* __restrict__ edata)
{
    int e = blockIdx.x * 256 + threadIdx.x;
    if (e >= N_EDGES) return;
    int row = ei[e];
    int slot = atomicAdd(&rs[row], 1) + bsum[row >> 8];
    ecol[slot] = ei[N_EDGES + e];
    edata[slot] = make_float4(a_vals[e], efeat[e * 3], efeat[e * 3 + 1], efeat[e * 3 + 2]);
}

// ---------------------------------------------------------------------------
// K_edge1: weight-free CSR reduction, layer 1. Zero LDS, max occupancy —
// the gather chain (ecol[k] -> x[col]) is latency-bound and needs waves.
// Lane = (node, f<10). 2-way unroll keeps two gather chains in flight.
// PQ1[n,50] = [P0|P1|P2|P3|Q].
// ---------------------------------------------------------------------------
__global__ __launch_bounds__(256) void k_edge1(
    const float* __restrict__ x,
    const int* __restrict__ rs, const int* __restrict__ bsum,
    const int* __restrict__ ecol, const float4* __restrict__ edata,
    float* __restrict__ PQ1)
{
    int idx = blockIdx.x * 256 + threadIdx.x;   // 3750 blocks exact
    int node = idx >> 4, f = idx & 15;
    if (f >= F_INQ) return;
    int end = rs[node] + bsum[node >> 8];
    int start = (node == 0) ? 0 : (rs[node - 1] + bsum[(node - 1) >> 8]);
    float p0 = 0.f, p1 = 0.f, p2 = 0.f, p3 = 0.f, q = 0.f;
    int k = start;
    for (; k + 2 <= end; k += 2) {
        int c0 = ecol[k], c1 = ecol[k + 1];
        float4 e0 = edata[k], e1 = edata[k + 1];
        float x0 = x[c0 * F_INQ + f];
        float x1 = x[c1 * F_INQ + f];
        p0 += x0;        p0 += x1;
        p1 += e0.y * x0; p1 += e1.y * x1;
        p2 += e0.z * x0; p2 += e1.z * x1;
        p3 += e0.w * x0; p3 += e1.w * x1;
        q  += e0.x * x0; q  += e1.x * x1;
    }
    if (k < end) {
        int c0 = ecol[k];
        float4 e0 = edata[k];
        float x0 = x[c0 * F_INQ + f];
        p0 += x0;
        p1 += e0.y * x0;
        p2 += e0.z * x0;
        p3 += e0.w * x0;
        q  += e0.x * x0;
    }
    float* P = PQ1 + node * 50;
    P[f]      = p0;
    P[10 + f] = p1;
    P[20 + f] = p2;
    P[30 + f] = p3;
    P[40 + f] = q;
}

// ---------------------------------------------------------------------------
// K_tf1: per-node transform 1. Thread = (node, o<16), o FIXED per thread so
// 60 weight floats live in VGPRs; grid-stride over nodes (16 nodes/block/iter).
//   c1 = relu(P0@be1 + sum_s Ps@We1_s + x_self@root1 + bias1)
//   g1 = relu(Q@Wg1 + b_gcn1)
// Output interleaved g1c1[n,32] = [g1(16)|c1(16)].
// ---------------------------------------------------------------------------
__global__ __launch_bounds__(256, 4) void k_tf1(
    const float* __restrict__ PQ1,
    const float* __restrict__ x,
    const float* __restrict__ Wg1,   // [10,16]
    const float* __restrict__ We1,   // [3,160]
    const float* __restrict__ be1,   // [160]
    const float* __restrict__ root1, // [10,16]
    const float* __restrict__ bias1, // [16]
    const float* __restrict__ bg1,   // [16]
    float* __restrict__ g1c1)
{
    // LDS: wg(160)|w0|w1|w2|bm|rt (160 each) | bias1(16) | bg1(16)
    __shared__ float w[6 * 160 + 32];
    for (int t = threadIdx.x; t < 6 * 160 + 32; t += 256) {
        float v;
        if (t < 960) {
            int slot = t / 160, r = t - slot * 160;
            if (slot == 0)      v = Wg1[r];
            else if (slot <= 3) v = We1[(slot - 1) * 160 + r];
            else if (slot == 4) v = be1[r];
            else                v = root1[r];
        } else if (t < 976) v = bias1[t - 960];
        else                v = bg1[t - 976];
        w[t] = v;
    }
    __syncthreads();
    int o = threadIdx.x & 15;
    int ngrp = threadIdx.x >> 4;         // 0..15
    float wg[10], w0[10], w1[10], w2[10], bm[10], rt[10];
#pragma unroll
    for (int f = 0; f < 10; ++f) {
        wg[f] = w[f * 16 + o];
        w0[f] = w[160 + f * 16 + o];
        w1[f] = w[320 + f * 16 + o];
        w2[f] = w[480 + f * 16 + o];
        bm[f] = w[640 + f * 16 + o];
        rt[f] = w[800 + f * 16 + o];
    }
    float bia = w[960 + o], bgv = w[976 + o];
    for (int node = blockIdx.x * 16 + ngrp; node < N_NODES; node += gridDim.x * 16) {
        const float* P = PQ1 + node * 50;
        const float* xs = x + node * F_INQ;
        float ac = bia, ag = bgv;
#pragma unroll
        for (int f = 0; f < 10; ++f) {
            ac += P[f] * bm[f] + P[10 + f] * w0[f] + P[20 + f] * w1[f]
                + P[30 + f] * w2[f] + xs[f] * rt[f];
            ag += P[40 + f] * wg[f];
        }
        g1c1[node * 32 + o]      = ag > 0.f ? ag : 0.f;
        g1c1[node * 32 + 16 + o] = ac > 0.f ? ac : 0.f;
    }
}

// ---------------------------------------------------------------------------
// K_edge2: weight-free CSR reduction, layer 2. Zero LDS, max occupancy.
// Lane = (node, f<16). 2-way unroll. PQ2[n,80] = [P0|P1|P2|P3|Q] (16 each);
// P* over c1, Q over a*g1.
// ---------------------------------------------------------------------------
__global__ __launch_bounds__(256) void k_edge2(
    const float* __restrict__ g1c1,
    const int* __restrict__ rs, const int* __restrict__ bsum,
    const int* __restrict__ ecol, const float4* __restrict__ edata,
    float* __restrict__ PQ2)
{
    int idx = blockIdx.x * 256 + threadIdx.x;   // 3750 blocks exact
    int node = idx >> 4, f = idx & 15;
    int end = rs[node] + bsum[node >> 8];
    int start = (node == 0) ? 0 : (rs[node - 1] + bsum[(node - 1) >> 8]);
    float p0 = 0.f, p1 = 0.f, p2 = 0.f, p3 = 0.f, q = 0.f;
    int k = start;
    for (; k + 2 <= end; k += 2) {
        int c0 = ecol[k], c1 = ecol[k + 1];
        float4 e0 = edata[k], e1 = edata[k + 1];
        float g0 = g1c1[c0 * 32 + f],      g1v = g1c1[c1 * 32 + f];
        float v0 = g1c1[c0 * 32 + 16 + f], v1 = g1c1[c1 * 32 + 16 + f];
        p0 += v0;        p0 += v1;
        p1 += e0.y * v0; p1 += e1.y * v1;
        p2 += e0.z * v0; p2 += e1.z * v1;
        p3 += e0.w * v0; p3 += e1.w * v1;
        q  += e0.x * g0; q  += e1.x * g1v;
    }
    if (k < end) {
        int c0 = ecol[k];
        float4 e0 = edata[k];
        float g0 = g1c1[c0 * 32 + f];
        float v0 = g1c1[c0 * 32 + 16 + f];
        p0 += v0;
        p1 += e0.y * v0;
        p2 += e0.z * v0;
        p3 += e0.w * v0;
        q  += e0.x * g0;
    }
    float* P = PQ2 + node * 80;
    P[f]      = p0;
    P[16 + f] = p1;
    P[32 + f] = p2;
    P[48 + f] = p3;
    P[64 + f] = q;
}

// ---------------------------------------------------------------------------
// K_tf2pool: per-node transform 2 FUSED with per-graph sum pooling.
// Grid-stride over contiguous 16-node chunks (so sorted seg run-detect works).
// Thread = (nh<8, o<32), o fixed -> 96 weight floats in VGPRs; 2 passes of 8
// nodes per chunk -> val[16][64] in LDS = [g2(32)|c2(32)] per node.
// Then 64 channel-threads run-detect over the chunk's sorted seg and emit one
// atomicAdd per (graph-run, channel) into pool[G,64]. g2c2 never exists.
// ---------------------------------------------------------------------------
__global__ __launch_bounds__(256, 3) void k_tf2pool(
    const float* __restrict__ PQ2,
    const float* __restrict__ g1c1,
    const int* __restrict__ seg,
    const float* __restrict__ Wg2,   // [16,32]
    const float* __restrict__ We2,   // [3,512]
    const float* __restrict__ be2,   // [512]
    const float* __restrict__ root2, // [16,32]
    const float* __restrict__ bias2, // [32]
    const float* __restrict__ bg2,   // [32]
    float* __restrict__ pool)
{
    // w: wg(512)|w0|w1|w2(@512,1024,1536)|bm=be2(@2048)|rt=root2(@2560)|bias2(@3072)|bg2(@3104)
    __shared__ float w[6 * 512 + 64];
    __shared__ float val[16][64];
    __shared__ int   sseg[16];
    for (int t = threadIdx.x; t < 6 * 512 + 64; t += 256) {
        float v;
        if (t < 3072) {
            int slot = t >> 9, r = t & 511;
            if (slot == 0)      v = Wg2[r];
            else if (slot <= 3) v = We2[(slot - 1) * 512 + r];
            else if (slot == 4) v = be2[r];
            else                v = root2[r];
        } else if (t < 3104) v = bias2[t - 3072];
        else                 v = bg2[t - 3104];
        w[t] = v;
    }
    __syncthreads();
    int o = threadIdx.x & 31;
    int nh = threadIdx.x >> 5;           // 0..7
    float wg[16], w0[16], w1[16], w2[16], bm[16], rt[16];
#pragma unroll
    for (int f = 0; f < 16; ++f) {
        wg[f] = w[f * 32 + o];
        w0[f] = w[512 + f * 32 + o];
        w1[f] = w[1024 + f * 32 + o];
        w2[f] = w[1536 + f * 32 + o];
        bm[f] = w[2048 + f * 32 + o];
        rt[f] = w[2560 + f * 32 + o];
    }
    float bia = w[3072 + o], bgv = w[3104 + o];
    for (int chunk = blockIdx.x; chunk < N_CHUNK; chunk += gridDim.x) {
        int base = chunk * 16;
        if (threadIdx.x < 16) sseg[threadIdx.x] = seg[base + threadIdx.x];
#pragma unroll
        for (int pass = 0; pass < 2; ++pass) {
            int n = pass * 8 + nh;
            const float* P = PQ2 + (size_t)(base + n) * 80;
            const float* cs = g1c1 + (size_t)(base + n) * 32 + 16;   // c1 self
            float ac = bia, ag = bgv;
#pragma unroll
            for (int f = 0; f < 16; ++f) {
                ac += P[f] * bm[f] + P[16 + f] * w0[f] + P[32 + f] * w1[f]
                    + P[48 + f] * w2[f] + cs[f] * rt[f];
                ag += P[64 + f] * wg[f];
            }
            val[n][o]      = ag > 0.f ? ag : 0.f;   // g2
            val[n][32 + o] = ac > 0.f ? ac : 0.f;   // c2
        }
        __syncthreads();
        if (threadIdx.x < 64) {
            int c = threadIdx.x;
            float acc = val[0][c];
            int curg = sseg[0];
            for (int n = 1; n < 16; ++n) {
                int gn = sseg[n];
                if (gn != curg) {
                    atomicAdd(&pool[curg * 64 + c], acc);
                    acc = 0.f;
                    curg = gn;
                }
                acc += val[n][c];
            }
            atomicAdd(&pool[curg * 64 + c], acc);
        }
        __syncthreads();
    }
}

// ---------------------------------------------------------------------------
// K_head: 4 graphs per block (64 threads each = one wave per graph).
// Reads pool[G,64] (131 KB total) -> fused MLP head -> sigmoid.
// ---------------------------------------------------------------------------
__global__ __launch_bounds__(256) void k_head(
    const float* __restrict__ pool,
    const float* __restrict__ Wd1, const float* __restrict__ bd1,
    const float* __restrict__ Wd2, const float* __restrict__ bd2,
    const float* __restrict__ Wo,  const float* __restrict__ bo,
    float* __restrict__ out)
{
    __shared__ float pl[4][64];
    __shared__ float h1s[4][16];
    __shared__ float h2s[4][8];
    int q = threadIdx.x >> 6, t = threadIdx.x & 63;
    int g = blockIdx.x * 4 + q;
    pl[q][t] = pool[g * 64 + t];
    __syncthreads();
    if (t < 16) {
        float a = bd1[t];
        for (int k = 0; k < 64; ++k) a += pl[q][k] * Wd1[k * 16 + t];
        h1s[q][t] = a > 0.f ? a : 0.f;
    }
    __syncthreads();
    if (t < 8) {
        float a = bd2[t];
        for (int k = 0; k < 16; ++k) a += h1s[q][k] * Wd2[k * 8 + t];
        h2s[q][t] = a > 0.f ? a : 0.f;
    }
    __syncthreads();
    if (t == 0) {
        float a = bo[0];
        for (int k = 0; k < 8; ++k) a += h2s[q][k] * Wo[k];
        out[g] = 1.f / (1.f + expf(-a));
    }
}

// ---------------------------------------------------------------------------
// Workspace layout (~44 MB):
//   edata E*float4 | PQ1 N*50 | g1c1 N*32 | PQ2 N*80 (floats)
//   rs[N] | pool[G*64] | bsum[256] | ecol[E]
//   (rs and pool contiguous -> single memset zeroes both)
// ---------------------------------------------------------------------------
extern "C" void kernel_launch(void* const* d_in, const int* in_sizes, int n_in,
                              void* d_out, int out_size, void* d_ws, size_t ws_size,
                              hipStream_t stream)
{
    const float* x      = (const float*)d_in[0];
    const float* a_vals = (const float*)d_in[1];
    const float* efeat  = (const float*)d_in[2];
    const int*   ei     = (const int*)d_in[3];
    const int*   seg    = (const int*)d_in[4];
    const float* Wg1    = (const float*)d_in[5];
    const float* bg1    = (const float*)d_in[6];
    const float* Wg2    = (const float*)d_in[7];
    const float* bg2    = (const float*)d_in[8];
    const float* We1    = (const float*)d_in[9];
    const float* be1    = (const float*)d_in[10];
    const float* root1  = (const float*)d_in[11];
    const float* bias1  = (const float*)d_in[12];
    const float* We2    = (const float*)d_in[13];
    const float* be2    = (const float*)d_in[14];
    const float* root2  = (const float*)d_in[15];
    const float* bias2  = (const float*)d_in[16];
    const float* Wd1    = (const float*)d_in[17];
    const float* bd1    = (const float*)d_in[18];
    const float* Wd2    = (const float*)d_in[19];
    const float* bd2    = (const float*)d_in[20];
    const float* Wo     = (const float*)d_in[21];
    const float* bo     = (const float*)d_in[22];

    float4* edata = (float4*)d_ws;
    float*  PQ1  = (float*)(edata + N_EDGES);
    float*  g1c1 = PQ1 + (size_t)N_NODES * 50;
    float*  PQ2  = g1c1 + (size_t)N_NODES * 32;
    int*    rs   = (int*)(PQ2 + (size_t)N_NODES * 80);
    float*  pool = (float*)(rs + N_NODES);
    int*    bsum = (int*)(pool + (size_t)G_DIM * 64);
    int*    ecol = bsum + 256;
    float*  out  = (float*)d_out;

    // zero rs (degree counters) and pool (atomic accumulators) in one shot
    hipMemsetAsync(rs, 0, sizeof(int) * (N_NODES + G_DIM * 64), stream);

    // CSR build
    k_deg    <<<NB_EDGE, 256, 0, stream>>>(ei, rs);
    k_scan_a <<<NB_SCAN, 256, 0, stream>>>(rs, bsum);
    k_scan_b <<<1, 256, 0, stream>>>(bsum);
    k_fill   <<<NB_EDGE, 256, 0, stream>>>(ei, a_vals, efeat, rs, bsum, ecol, edata);

    // Layer 1: weight-free edge reduction + node transform
    k_edge1<<<N_NODES * 16 / 256, 256, 0, stream>>>(x, rs, bsum, ecol, edata, PQ1);
    k_tf1  <<<1280, 256, 0, stream>>>(PQ1, x, Wg1, We1, be1, root1, bias1, bg1, g1c1);

    // Layer 2: edge reduction + transform fused with per-graph pooling
    k_edge2<<<N_NODES * 16 / 256, 256, 0, stream>>>(g1c1, rs, bsum, ecol, edata, PQ2);
    k_tf2pool<<<1280, 256, 0, stream>>>(PQ2, g1c1, seg, Wg2, We2, be2, root2,
                                        bias2, bg2, pool);

    // MLP head
    k_head<<<G_DIM / 4, 256, 0, stream>>>(pool, Wd1, bd1, Wd2, bd2, Wo, bo, out);
}

// Round 3
// 228.874 us; speedup vs baseline: 1.0721x; 1.0489x over previous
//
#include <hip/hip_runtime.h>
#include <math.h>

#define N_NODES 60000
#define N_EDGES 240000
#define F_INQ 10
#define G_DIM 512
#define NB_SCAN ((N_NODES + 255) / 256)   // 235
#define NB_EDGE ((N_EDGES + 255) / 256)   // 938
#define N_CHUNK (N_NODES / 16)            // 3750 16-node chunks

// ===========================================================================
// CSR build: deg -> block scan -> block-sum scan -> fill with reordered edge
// records. After k_fill: global end(i) = rs[i]+bsum[i>>8].
// ===========================================================================
__global__ __launch_bounds__(256) void k_deg(
    const int* __restrict__ ei, int* __restrict__ rs)
{
    int e = blockIdx.x * 256 + threadIdx.x;
    if (e < N_EDGES) atomicAdd(&rs[ei[e]], 1);
}

__global__ __launch_bounds__(256) void k_scan_a(
    int* __restrict__ rs, int* __restrict__ bsum)
{
    __shared__ int s[256];
    int i = blockIdx.x * 256 + threadIdx.x;
    int v = (i < N_NODES) ? rs[i] : 0;
    s[threadIdx.x] = v;
    __syncthreads();
    for (int off = 1; off < 256; off <<= 1) {
        int t = (threadIdx.x >= off) ? s[threadIdx.x - off] : 0;
        __syncthreads();
        s[threadIdx.x] += t;
        __syncthreads();
    }
    if (i < N_NODES) rs[i] = s[threadIdx.x] - v;  // block-local exclusive
    if (threadIdx.x == 255) bsum[blockIdx.x] = s[255];
}

__global__ __launch_bounds__(256) void k_scan_b(int* __restrict__ bsum)
{
    __shared__ int s[256];
    int v = (threadIdx.x < NB_SCAN) ? bsum[threadIdx.x] : 0;
    s[threadIdx.x] = v;
    __syncthreads();
    for (int off = 1; off < 256; off <<= 1) {
        int t = (threadIdx.x >= off) ? s[threadIdx.x - off] : 0;
        __syncthreads();
        s[threadIdx.x] += t;
        __syncthreads();
    }
    if (threadIdx.x < NB_SCAN) bsum[threadIdx.x] = s[threadIdx.x] - v;  // exclusive
}

__global__ __launch_bounds__(256) void k_fill(
    const int* __restrict__ ei, const float* __restrict__ a_vals,
    const float* __restrict__ efeat,
    int* __restrict__ rs, const int* __restrict__ bsum,
    int* __restrict__ ecol, float4* __restrict__ edata)
{
    int e = blockIdx.x * 256 + threadIdx.x;
    if (e >= N_EDGES) return;
    int row = ei[e];
    int slot = atomicAdd(&rs[row], 1) + bsum[row >> 8];
    ecol[slot] = ei[N_EDGES + e];
    edata[slot] = make_float4(a_vals[e], efeat[e * 3], efeat[e * 3 + 1], efeat[e * 3 + 2]);
}

// ---------------------------------------------------------------------------
// K_edge1: weight-free CSR reduction, layer 1. Zero LDS, max occupancy —
// the gather chain (ecol[k] -> x[col]) is latency-bound and needs waves.
// Lane = (node, f<10). 2-way unroll keeps two gather chains in flight.
// PQ1[n,50] = [P0|P1|P2|P3|Q].
// ---------------------------------------------------------------------------
__global__ __launch_bounds__(256) void k_edge1(
    const float* __restrict__ x,
    const int* __restrict__ rs, const int* __restrict__ bsum,
    const int* __restrict__ ecol, const float4* __restrict__ edata,
    float* __restrict__ PQ1)
{
    int idx = blockIdx.x * 256 + threadIdx.x;   // 3750 blocks exact
    int node = idx >> 4, f = idx & 15;
    if (f >= F_INQ) return;
    int end = rs[node] + bsum[node >> 8];
    int start = (node == 0) ? 0 : (rs[node - 1] + bsum[(node - 1) >> 8]);
    float p0 = 0.f, p1 = 0.f, p2 = 0.f, p3 = 0.f, q = 0.f;
    int k = start;
    for (; k + 2 <= end; k += 2) {
        int c0 = ecol[k], c1 = ecol[k + 1];
        float4 e0 = edata[k], e1 = edata[k + 1];
        float x0 = x[c0 * F_INQ + f];
        float x1 = x[c1 * F_INQ + f];
        p0 += x0;        p0 += x1;
        p1 += e0.y * x0; p1 += e1.y * x1;
        p2 += e0.z * x0; p2 += e1.z * x1;
        p3 += e0.w * x0; p3 += e1.w * x1;
        q  += e0.x * x0; q  += e1.x * x1;
    }
    if (k < end) {
        int c0 = ecol[k];
        float4 e0 = edata[k];
        float x0 = x[c0 * F_INQ + f];
        p0 += x0;
        p1 += e0.y * x0;
        p2 += e0.z * x0;
        p3 += e0.w * x0;
        q  += e0.x * x0;
    }
    float* P = PQ1 + node * 50;
    P[f]      = p0;
    P[10 + f] = p1;
    P[20 + f] = p2;
    P[30 + f] = p3;
    P[40 + f] = q;
}

// ---------------------------------------------------------------------------
// K_tf1: per-node transform 1. Thread = (node, o<16). Weights stay in LDS
// and are read inside the FMA loop (NO VGPR preload -> no scratch spill;
// w[f*16+o] is stride-1 across the 32 consecutive lanes -> conflict-free).
//   c1 = relu(P0@be1 + sum_s Ps@We1_s + x_self@root1 + bias1)
//   g1 = relu(Q@Wg1 + b_gcn1)
// Output interleaved g1c1[n,32] = [g1(16)|c1(16)].
// ---------------------------------------------------------------------------
__global__ __launch_bounds__(256) void k_tf1(
    const float* __restrict__ PQ1,
    const float* __restrict__ x,
    const float* __restrict__ Wg1,   // [10,16]
    const float* __restrict__ We1,   // [3,160]
    const float* __restrict__ be1,   // [160]
    const float* __restrict__ root1, // [10,16]
    const float* __restrict__ bias1, // [16]
    const float* __restrict__ bg1,   // [16]
    float* __restrict__ g1c1)
{
    // LDS: wg(160)|w0|w1|w2(@160,320,480)|bm=be1(@640)|rt=root1(@800)|bias1(@960)|bg1(@976)
    __shared__ float w[6 * 160 + 32];
    for (int t = threadIdx.x; t < 6 * 160 + 32; t += 256) {
        float v;
        if (t < 960) {
            int slot = t / 160, r = t - slot * 160;
            if (slot == 0)      v = Wg1[r];
            else if (slot <= 3) v = We1[(slot - 1) * 160 + r];
            else if (slot == 4) v = be1[r];
            else                v = root1[r];
        } else if (t < 976) v = bias1[t - 960];
        else                v = bg1[t - 976];
        w[t] = v;
    }
    __syncthreads();
    int o = threadIdx.x & 15;
    int ngrp = threadIdx.x >> 4;         // 0..15
    for (int node = blockIdx.x * 16 + ngrp; node < N_NODES; node += gridDim.x * 16) {
        const float* P = PQ1 + node * 50;
        const float* xs = x + node * F_INQ;
        float ac = w[960 + o], ag = w[976 + o];
#pragma unroll
        for (int f = 0; f < 10; ++f) {
            ac += P[f]      * w[640 + f * 16 + o]
                + P[10 + f] * w[160 + f * 16 + o]
                + P[20 + f] * w[320 + f * 16 + o]
                + P[30 + f] * w[480 + f * 16 + o]
                + xs[f]     * w[800 + f * 16 + o];
            ag += P[40 + f] * w[f * 16 + o];
        }
        g1c1[node * 32 + o]      = ag > 0.f ? ag : 0.f;
        g1c1[node * 32 + 16 + o] = ac > 0.f ? ac : 0.f;
    }
}

// ---------------------------------------------------------------------------
// K_edge2: weight-free CSR reduction, layer 2. Zero LDS, max occupancy.
// Lane = (node, f<16). 2-way unroll. PQ2[n,80] = [P0|P1|P2|P3|Q] (16 each);
// P* over c1, Q over a*g1.
// ---------------------------------------------------------------------------
__global__ __launch_bounds__(256) void k_edge2(
    const float* __restrict__ g1c1,
    const int* __restrict__ rs, const int* __restrict__ bsum,
    const int* __restrict__ ecol, const float4* __restrict__ edata,
    float* __restrict__ PQ2)
{
    int idx = blockIdx.x * 256 + threadIdx.x;   // 3750 blocks exact
    int node = idx >> 4, f = idx & 15;
    int end = rs[node] + bsum[node >> 8];
    int start = (node == 0) ? 0 : (rs[node - 1] + bsum[(node - 1) >> 8]);
    float p0 = 0.f, p1 = 0.f, p2 = 0.f, p3 = 0.f, q = 0.f;
    int k = start;
    for (; k + 2 <= end; k += 2) {
        int c0 = ecol[k], c1 = ecol[k + 1];
        float4 e0 = edata[k], e1 = edata[k + 1];
        float g0 = g1c1[c0 * 32 + f],      g1v = g1c1[c1 * 32 + f];
        float v0 = g1c1[c0 * 32 + 16 + f], v1 = g1c1[c1 * 32 + 16 + f];
        p0 += v0;        p0 += v1;
        p1 += e0.y * v0; p1 += e1.y * v1;
        p2 += e0.z * v0; p2 += e1.z * v1;
        p3 += e0.w * v0; p3 += e1.w * v1;
        q  += e0.x * g0; q  += e1.x * g1v;
    }
    if (k < end) {
        int c0 = ecol[k];
        float4 e0 = edata[k];
        float g0 = g1c1[c0 * 32 + f];
        float v0 = g1c1[c0 * 32 + 16 + f];
        p0 += v0;
        p1 += e0.y * v0;
        p2 += e0.z * v0;
        p3 += e0.w * v0;
        q  += e0.x * g0;
    }
    float* P = PQ2 + node * 80;
    P[f]      = p0;
    P[16 + f] = p1;
    P[32 + f] = p2;
    P[48 + f] = p3;
    P[64 + f] = q;
}

// ---------------------------------------------------------------------------
// K_tf2pool: per-node transform 2 FUSED with per-graph sum pooling.
// Grid-stride over contiguous 16-node chunks (so sorted seg run-detect works).
// Thread = (nh<8, o<32); weights read DIRECTLY from LDS in the FMA loop
// (no VGPR preload -> no scratch spill; w[f*32+o] is conflict-free).
// 2 passes of 8 nodes per chunk -> val[16][64] in LDS = [g2(32)|c2(32)].
// Then 64 channel-threads run-detect over the chunk's sorted seg and emit one
// atomicAdd per (graph-run, channel) into pool[G,64]. g2c2 never exists.
// ---------------------------------------------------------------------------
__global__ __launch_bounds__(256) void k_tf2pool(
    const float* __restrict__ PQ2,
    const float* __restrict__ g1c1,
    const int* __restrict__ seg,
    const float* __restrict__ Wg2,   // [16,32]
    const float* __restrict__ We2,   // [3,512]
    const float* __restrict__ be2,   // [512]
    const float* __restrict__ root2, // [16,32]
    const float* __restrict__ bias2, // [32]
    const float* __restrict__ bg2,   // [32]
    float* __restrict__ pool)
{
    // w: wg(512)|w0|w1|w2(@512,1024,1536)|bm=be2(@2048)|rt=root2(@2560)|bias2(@3072)|bg2(@3104)
    __shared__ float w[6 * 512 + 64];
    __shared__ float val[16][64];
    __shared__ int   sseg[16];
    for (int t = threadIdx.x; t < 6 * 512 + 64; t += 256) {
        float v;
        if (t < 3072) {
            int slot = t >> 9, r = t & 511;
            if (slot == 0)      v = Wg2[r];
            else if (slot <= 3) v = We2[(slot - 1) * 512 + r];
            else if (slot == 4) v = be2[r];
            else                v = root2[r];
        } else if (t < 3104) v = bias2[t - 3072];
        else                 v = bg2[t - 3104];
        w[t] = v;
    }
    __syncthreads();
    int o = threadIdx.x & 31;
    int nh = threadIdx.x >> 5;           // 0..7
    for (int chunk = blockIdx.x; chunk < N_CHUNK; chunk += gridDim.x) {
        int base = chunk * 16;
        if (threadIdx.x < 16) sseg[threadIdx.x] = seg[base + threadIdx.x];
#pragma unroll
        for (int pass = 0; pass < 2; ++pass) {
            int n = pass * 8 + nh;
            const float* P = PQ2 + (size_t)(base + n) * 80;
            const float* cs = g1c1 + (size_t)(base + n) * 32 + 16;   // c1 self
            float ac = w[3072 + o], ag = w[3104 + o];
#pragma unroll
            for (int f = 0; f < 16; ++f) {
                ac += P[f]      * w[2048 + f * 32 + o]
                    + P[16 + f] * w[512  + f * 32 + o]
                    + P[32 + f] * w[1024 + f * 32 + o]
                    + P[48 + f] * w[1536 + f * 32 + o]
                    + cs[f]     * w[2560 + f * 32 + o];
                ag += P[64 + f] * w[f * 32 + o];
            }
            val[n][o]      = ag > 0.f ? ag : 0.f;   // g2
            val[n][32 + o] = ac > 0.f ? ac : 0.f;   // c2
        }
        __syncthreads();
        if (threadIdx.x < 64) {
            int c = threadIdx.x;
            float acc = val[0][c];
            int curg = sseg[0];
            for (int n = 1; n < 16; ++n) {
                int gn = sseg[n];
                if (gn != curg) {
                    atomicAdd(&pool[curg * 64 + c], acc);
                    acc = 0.f;
                    curg = gn;
                }
                acc += val[n][c];
            }
            atomicAdd(&pool[curg * 64 + c], acc);
        }
        __syncthreads();
    }
}

// ---------------------------------------------------------------------------
// K_head: 4 graphs per block (64 threads each = one wave per graph).
// Reads pool[G,64] (131 KB total) -> fused MLP head -> sigmoid.
// ---------------------------------------------------------------------------
__global__ __launch_bounds__(256) void k_head(
    const float* __restrict__ pool,
    const float* __restrict__ Wd1, const float* __restrict__ bd1,
    const float* __restrict__ Wd2, const float* __restrict__ bd2,
    const float* __restrict__ Wo,  const float* __restrict__ bo,
    float* __restrict__ out)
{
    __shared__ float pl[4][64];
    __shared__ float h1s[4][16];
    __shared__ float h2s[4][8];
    int q = threadIdx.x >> 6, t = threadIdx.x & 63;
    int g = blockIdx.x * 4 + q;
    pl[q][t] = pool[g * 64 + t];
    __syncthreads();
    if (t < 16) {
        float a = bd1[t];
        for (int k = 0; k < 64; ++k) a += pl[q][k] * Wd1[k * 16 + t];
        h1s[q][t] = a > 0.f ? a : 0.f;
    }
    __syncthreads();
    if (t < 8) {
        float a = bd2[t];
        for (int k = 0; k < 16; ++k) a += h1s[q][k] * Wd2[k * 8 + t];
        h2s[q][t] = a > 0.f ? a : 0.f;
    }
    __syncthreads();
    if (t == 0) {
        float a = bo[0];
        for (int k = 0; k < 8; ++k) a += h2s[q][k] * Wo[k];
        out[g] = 1.f / (1.f + expf(-a));
    }
}

// ---------------------------------------------------------------------------
// Workspace layout (~44 MB):
//   edata E*float4 | PQ1 N*50 | g1c1 N*32 | PQ2 N*80 (floats)
//   rs[N] | pool[G*64] | bsum[256] | ecol[E]
//   (rs and pool contiguous -> single memset zeroes both)
// ---------------------------------------------------------------------------
extern "C" void kernel_launch(void* const* d_in, const int* in_sizes, int n_in,
                              void* d_out, int out_size, void* d_ws, size_t ws_size,
                              hipStream_t stream)
{
    const float* x      = (const float*)d_in[0];
    const float* a_vals = (const float*)d_in[1];
    const float* efeat  = (const float*)d_in[2];
    const int*   ei     = (const int*)d_in[3];
    const int*   seg    = (const int*)d_in[4];
    const float* Wg1    = (const float*)d_in[5];
    const float* bg1    = (const float*)d_in[6];
    const float* Wg2    = (const float*)d_in[7];
    const float* bg2    = (const float*)d_in[8];
    const float* We1    = (const float*)d_in[9];
    const float* be1    = (const float*)d_in[10];
    const float* root1  = (const float*)d_in[11];
    const float* bias1  = (const float*)d_in[12];
    const float* We2    = (const float*)d_in[13];
    const float* be2    = (const float*)d_in[14];
    const float* root2  = (const float*)d_in[15];
    const float* bias2  = (const float*)d_in[16];
    const float* Wd1    = (const float*)d_in[17];
    const float* bd1    = (const float*)d_in[18];
    const float* Wd2    = (const float*)d_in[19];
    const float* bd2    = (const float*)d_in[20];
    const float* Wo     = (const float*)d_in[21];
    const float* bo     = (const float*)d_in[22];

    float4* edata = (float4*)d_ws;
    float*  PQ1  = (float*)(edata + N_EDGES);
    float*  g1c1 = PQ1 + (size_t)N_NODES * 50;
    float*  PQ2  = g1c1 + (size_t)N_NODES * 32;
    int*    rs   = (int*)(PQ2 + (size_t)N_NODES * 80);
    float*  pool = (float*)(rs + N_NODES);
    int*    bsum = (int*)(pool + (size_t)G_DIM * 64);
    int*    ecol = bsum + 256;
    float*  out  = (float*)d_out;

    // zero rs (degree counters) and pool (atomic accumulators) in one shot
    hipMemsetAsync(rs, 0, sizeof(int) * (N_NODES + G_DIM * 64), stream);

    // CSR build
    k_deg    <<<NB_EDGE, 256, 0, stream>>>(ei, rs);
    k_scan_a <<<NB_SCAN, 256, 0, stream>>>(rs, bsum);
    k_scan_b <<<1, 256, 0, stream>>>(bsum);
    k_fill   <<<NB_EDGE, 256, 0, stream>>>(ei, a_vals, efeat, rs, bsum, ecol, edata);

    // Layer 1: weight-free edge reduction + node transform
    k_edge1<<<N_NODES * 16 / 256, 256, 0, stream>>>(x, rs, bsum, ecol, edata, PQ1);
    k_tf1  <<<1280, 256, 0, stream>>>(PQ1, x, Wg1, We1, be1, root1, bias1, bg1, g1c1);

    // Layer 2: edge reduction + transform fused with per-graph pooling
    k_edge2<<<N_NODES * 16 / 256, 256, 0, stream>>>(g1c1, rs, bsum, ecol, edata, PQ2);
    k_tf2pool<<<1280, 256, 0, stream>>>(PQ2, g1c1, seg, Wg2, We2, be2, root2,
                                        bias2, bg2, pool);

    // MLP head
    k_head<<<G_DIM / 4, 256, 0, stream>>>(pool, Wd1, bd1, Wd2, bd2, Wo, bo, out);
}

// Round 4
// 194.427 us; speedup vs baseline: 1.2621x; 1.1772x over previous
//
#include <hip/hip_runtime.h>
#include <math.h>

#define N_NODES 60000
#define N_EDGES 240000
#define F_INQ 10
#define G_DIM 512
#define NB_SCAN ((N_NODES + 255) / 256)   // 235
#define NB_EDGE ((N_EDGES + 255) / 256)   // 938
#define NB_TILE ((N_NODES + 63) / 64)     // 938 64-node tiles
#define PQ1_STRIDE 56                     // 50 used, padded to 224B (16B-aligned rows)

// ===========================================================================
// CSR build: deg -> block scan -> block-sum scan (+ weight transpose) -> fill.
// After k_fill: global end(i) = rs[i]+bsum[i>>8].
// ===========================================================================
__global__ __launch_bounds__(256) void k_deg(
    const int* __restrict__ ei, int* __restrict__ rs)
{
    int e = blockIdx.x * 256 + threadIdx.x;
    if (e < N_EDGES) atomicAdd(&rs[ei[e]], 1);
}

__global__ __launch_bounds__(256) void k_scan_a(
    int* __restrict__ rs, int* __restrict__ bsum)
{
    __shared__ int s[256];
    int i = blockIdx.x * 256 + threadIdx.x;
    int v = (i < N_NODES) ? rs[i] : 0;
    s[threadIdx.x] = v;
    __syncthreads();
    for (int off = 1; off < 256; off <<= 1) {
        int t = (threadIdx.x >= off) ? s[threadIdx.x - off] : 0;
        __syncthreads();
        s[threadIdx.x] += t;
        __syncthreads();
    }
    if (i < N_NODES) rs[i] = s[threadIdx.x] - v;  // block-local exclusive
    if (threadIdx.x == 255) bsum[blockIdx.x] = s[255];
}

// ---------------------------------------------------------------------------
// k_scan_b + weight transpose (1 block; transpose is independent filler work).
// Wt1[32][64]: rows 0..15  = g1 out o: [0..9]=Wg1[f][o], [10]=bg1[o]
//              rows 16..31 = c1 out o: [0..9]=be1 col, [10..19]=We1_0,
//                [20..29]=We1_1, [30..39]=We1_2, [40..49]=root1, [50]=bias1[o]
// Wt2[64][96]: rows 0..31  = g2 out o: [0..15]=Wg2[f][o], [16]=bg2[o]
//              rows 32..63 = c2 out o: [0..15]=be2 col, [16..31]=We2_0,
//                [32..47]=We2_1, [48..63]=We2_2, [64..79]=root2, [80]=bias2[o]
// ---------------------------------------------------------------------------
__global__ __launch_bounds__(256) void k_scan_b(
    int* __restrict__ bsum,
    const float* __restrict__ Wg1, const float* __restrict__ bg1,
    const float* __restrict__ We1, const float* __restrict__ be1,
    const float* __restrict__ root1, const float* __restrict__ bias1,
    const float* __restrict__ Wg2, const float* __restrict__ bg2,
    const float* __restrict__ We2, const float* __restrict__ be2,
    const float* __restrict__ root2, const float* __restrict__ bias2,
    float* __restrict__ Wt1, float* __restrict__ Wt2)
{
    __shared__ int s[256];
    int v = (threadIdx.x < NB_SCAN) ? bsum[threadIdx.x] : 0;
    s[threadIdx.x] = v;
    __syncthreads();
    for (int off = 1; off < 256; off <<= 1) {
        int t = (threadIdx.x >= off) ? s[threadIdx.x - off] : 0;
        __syncthreads();
        s[threadIdx.x] += t;
        __syncthreads();
    }
    if (threadIdx.x < NB_SCAN) bsum[threadIdx.x] = s[threadIdx.x] - v;  // exclusive

    // ---- weight transposes (no sync needed; independent of scan) ----
    for (int i = threadIdx.x; i < 16 * 11; i += 256) {
        int o = i / 11, f = i - o * 11;
        Wt1[o * 64 + f] = (f < 10) ? Wg1[f * 16 + o] : bg1[o];
    }
    for (int i = threadIdx.x; i < 16 * 51; i += 256) {
        int o = i / 51, f = i - o * 51;
        float w;
        if      (f < 10) w = be1[f * 16 + o];
        else if (f < 20) w = We1[(f - 10) * 16 + o];
        else if (f < 30) w = We1[160 + (f - 20) * 16 + o];
        else if (f < 40) w = We1[320 + (f - 30) * 16 + o];
        else if (f < 50) w = root1[(f - 40) * 16 + o];
        else             w = bias1[o];
        Wt1[(16 + o) * 64 + f] = w;
    }
    for (int i = threadIdx.x; i < 32 * 17; i += 256) {
        int o = i / 17, f = i - o * 17;
        Wt2[o * 96 + f] = (f < 16) ? Wg2[f * 32 + o] : bg2[o];
    }
    for (int i = threadIdx.x; i < 32 * 81; i += 256) {
        int o = i / 81, f = i - o * 81;
        float w;
        if      (f < 16) w = be2[f * 32 + o];
        else if (f < 32) w = We2[(f - 16) * 32 + o];
        else if (f < 48) w = We2[512 + (f - 32) * 32 + o];
        else if (f < 64) w = We2[1024 + (f - 48) * 32 + o];
        else if (f < 80) w = root2[(f - 64) * 32 + o];
        else             w = bias2[o];
        Wt2[(32 + o) * 96 + f] = w;
    }
}

__global__ __launch_bounds__(256) void k_fill(
    const int* __restrict__ ei, const float* __restrict__ a_vals,
    const float* __restrict__ efeat,
    int* __restrict__ rs, const int* __restrict__ bsum,
    int* __restrict__ ecol, float4* __restrict__ edata)
{
    int e = blockIdx.x * 256 + threadIdx.x;
    if (e >= N_EDGES) return;
    int row = ei[e];
    int slot = atomicAdd(&rs[row], 1) + bsum[row >> 8];
    ecol[slot] = ei[N_EDGES + e];
    edata[slot] = make_float4(a_vals[e], efeat[e * 3], efeat[e * 3 + 1], efeat[e * 3 + 2]);
}

// ---------------------------------------------------------------------------
// K_edge1: weight-free CSR reduction, layer 1. Zero LDS, max occupancy.
// Lane = (node, f<10). 2-way unroll. PQ1[n, stride 56] = [P0|P1|P2|P3|Q].
// ---------------------------------------------------------------------------
__global__ __launch_bounds__(256) void k_edge1(
    const float* __restrict__ x,
    const int* __restrict__ rs, const int* __restrict__ bsum,
    const int* __restrict__ ecol, const float4* __restrict__ edata,
    float* __restrict__ PQ1)
{
    int idx = blockIdx.x * 256 + threadIdx.x;   // 3750 blocks exact
    int node = idx >> 4, f = idx & 15;
    if (f >= F_INQ) return;
    int end = rs[node] + bsum[node >> 8];
    int start = (node == 0) ? 0 : (rs[node - 1] + bsum[(node - 1) >> 8]);
    float p0 = 0.f, p1 = 0.f, p2 = 0.f, p3 = 0.f, q = 0.f;
    int k = start;
    for (; k + 2 <= end; k += 2) {
        int c0 = ecol[k], c1 = ecol[k + 1];
        float4 e0 = edata[k], e1 = edata[k + 1];
        float x0 = x[c0 * F_INQ + f];
        float x1 = x[c1 * F_INQ + f];
        p0 += x0;        p0 += x1;
        p1 += e0.y * x0; p1 += e1.y * x1;
        p2 += e0.z * x0; p2 += e1.z * x1;
        p3 += e0.w * x0; p3 += e1.w * x1;
        q  += e0.x * x0; q  += e1.x * x1;
    }
    if (k < end) {
        int c0 = ecol[k];
        float4 e0 = edata[k];
        float x0 = x[c0 * F_INQ + f];
        p0 += x0;
        p1 += e0.y * x0;
        p2 += e0.z * x0;
        p3 += e0.w * x0;
        q  += e0.x * x0;
    }
    float* P = PQ1 + (size_t)node * PQ1_STRIDE;
    P[f]      = p0;
    P[10 + f] = p1;
    P[20 + f] = p2;
    P[30 + f] = p3;
    P[40 + f] = q;
}

// ---------------------------------------------------------------------------
// K_tf1: transform 1, SGPR-weight formulation. Lane = node (64-node tile),
// wave = output-group. Inputs (PQ1 row 50 + x row 10) live in VGPRs via
// coalesced float4/float2 loads; weight rows are wave-uniform -> s_load into
// SGPRs -> v_fmac(sgpr, vgpr, vgpr), ZERO per-MAC LDS/VMEM.
// Each wave: 4 g1 outputs (10 MAC) + 4 c1 outputs (50 MAC).
// Output staged in LDS -> coalesced float4 stores of g1c1[n,32]=[g1|c1].
// ---------------------------------------------------------------------------
__global__ __launch_bounds__(256) void k_tf1(
    const float* __restrict__ PQ1,
    const float* __restrict__ x,
    const float* __restrict__ Wt1,
    float* __restrict__ g1c1)
{
    __shared__ float val[64][65];
    int tile = blockIdx.x;
    int lane = threadIdx.x & 63;
    int wv = __builtin_amdgcn_readfirstlane(threadIdx.x >> 6);   // 0..3
    int node = tile * 64 + lane;
    int nclamp = node < N_NODES ? node : N_NODES - 1;

    float pr[52];
    const float4* P4 = (const float4*)(PQ1 + (size_t)nclamp * PQ1_STRIDE);
#pragma unroll
    for (int i = 0; i < 13; ++i) {
        float4 t = P4[i];
        pr[i * 4] = t.x; pr[i * 4 + 1] = t.y; pr[i * 4 + 2] = t.z; pr[i * 4 + 3] = t.w;
    }
    float xs[10];
    const float2* X2 = (const float2*)(x + (size_t)nclamp * F_INQ);
#pragma unroll
    for (int i = 0; i < 5; ++i) {
        float2 t = X2[i];
        xs[i * 2] = t.x; xs[i * 2 + 1] = t.y;
    }

#pragma unroll
    for (int j = 0; j < 4; ++j) {        // g1 outputs
        const float* wr = Wt1 + (wv * 4 + j) * 64;
        float a = wr[10];
#pragma unroll
        for (int f = 0; f < 10; ++f) a = fmaf(wr[f], pr[40 + f], a);
        val[lane][wv * 4 + j] = a > 0.f ? a : 0.f;
    }
#pragma unroll
    for (int j = 0; j < 4; ++j) {        // c1 outputs
        const float* wr = Wt1 + (16 + wv * 4 + j) * 64;
        float a = wr[50];
#pragma unroll
        for (int f = 0; f < 40; ++f) a = fmaf(wr[f], pr[f], a);
#pragma unroll
        for (int f = 0; f < 10; ++f) a = fmaf(wr[40 + f], xs[f], a);
        val[lane][16 + wv * 4 + j] = a > 0.f ? a : 0.f;
    }
    __syncthreads();

    float4* G4 = (float4*)(g1c1 + (size_t)tile * 64 * 32);
#pragma unroll
    for (int k = 0; k < 2; ++k) {
        int fi4 = k * 256 + threadIdx.x;
        int n = fi4 >> 3, o4 = (fi4 & 7) * 4;
        if (tile * 64 + n < N_NODES)
            G4[fi4] = make_float4(val[n][o4], val[n][o4 + 1], val[n][o4 + 2], val[n][o4 + 3]);
    }
}

// ---------------------------------------------------------------------------
// K_edge2: weight-free CSR reduction, layer 2. Zero LDS, max occupancy.
// Lane = (node, f<16). 2-way unroll. PQ2[n,80] = [P0|P1|P2|P3|Q].
// ---------------------------------------------------------------------------
__global__ __launch_bounds__(256) void k_edge2(
    const float* __restrict__ g1c1,
    const int* __restrict__ rs, const int* __restrict__ bsum,
    const int* __restrict__ ecol, const float4* __restrict__ edata,
    float* __restrict__ PQ2)
{
    int idx = blockIdx.x * 256 + threadIdx.x;   // 3750 blocks exact
    int node = idx >> 4, f = idx & 15;
    int end = rs[node] + bsum[node >> 8];
    int start = (node == 0) ? 0 : (rs[node - 1] + bsum[(node - 1) >> 8]);
    float p0 = 0.f, p1 = 0.f, p2 = 0.f, p3 = 0.f, q = 0.f;
    int k = start;
    for (; k + 2 <= end; k += 2) {
        int c0 = ecol[k], c1 = ecol[k + 1];
        float4 e0 = edata[k], e1 = edata[k + 1];
        float g0 = g1c1[c0 * 32 + f],      g1v = g1c1[c1 * 32 + f];
        float v0 = g1c1[c0 * 32 + 16 + f], v1 = g1c1[c1 * 32 + 16 + f];
        p0 += v0;        p0 += v1;
        p1 += e0.y * v0; p1 += e1.y * v1;
        p2 += e0.z * v0; p2 += e1.z * v1;
        p3 += e0.w * v0; p3 += e1.w * v1;
        q  += e0.x * g0; q  += e1.x * g1v;
    }
    if (k < end) {
        int c0 = ecol[k];
        float4 e0 = edata[k];
        float g0 = g1c1[c0 * 32 + f];
        float v0 = g1c1[c0 * 32 + 16 + f];
        p0 += v0;
        p1 += e0.y * v0;
        p2 += e0.z * v0;
        p3 += e0.w * v0;
        q  += e0.x * g0;
    }
    float* P = PQ2 + (size_t)node * 80;
    P[f]      = p0;
    P[16 + f] = p1;
    P[32 + f] = p2;
    P[48 + f] = p3;
    P[64 + f] = q;
}

// ---------------------------------------------------------------------------
// K_tf2pool: transform 2 + per-graph pooling, SGPR-weight formulation.
// Lane = node (64-node tile), wave = output-group (8 g2 + 8 c2 outputs).
// Inputs (PQ2 row 80 + c1_self 16) in VGPRs; weights via wave-uniform s_load.
// Outputs -> LDS val[64][65], then 4x64 threads run-detect pool over sorted
// seg (one atomicAdd per (run, channel, quarter)). g2c2 never exists.
// ---------------------------------------------------------------------------
__global__ __launch_bounds__(256) void k_tf2pool(
    const float* __restrict__ PQ2,
    const float* __restrict__ g1c1,
    const int* __restrict__ seg,
    const float* __restrict__ Wt2,
    float* __restrict__ pool)
{
    __shared__ float val[64][65];
    __shared__ int sseg[64];
    int tile = blockIdx.x;
    int lane = threadIdx.x & 63;
    int wv = __builtin_amdgcn_readfirstlane(threadIdx.x >> 6);   // 0..3
    int node = tile * 64 + lane;
    int nclamp = node < N_NODES ? node : N_NODES - 1;

    if (threadIdx.x < 64) {
        int nd = tile * 64 + threadIdx.x;
        sseg[threadIdx.x] = (nd < N_NODES) ? seg[nd] : -1;
    }

    float pr[80];
    const float4* P4 = (const float4*)(PQ2 + (size_t)nclamp * 80);
#pragma unroll
    for (int i = 0; i < 20; ++i) {
        float4 t = P4[i];
        pr[i * 4] = t.x; pr[i * 4 + 1] = t.y; pr[i * 4 + 2] = t.z; pr[i * 4 + 3] = t.w;
    }
    float cs[16];
    const float4* C4 = (const float4*)(g1c1 + (size_t)nclamp * 32 + 16);
#pragma unroll
    for (int i = 0; i < 4; ++i) {
        float4 t = C4[i];
        cs[i * 4] = t.x; cs[i * 4 + 1] = t.y; cs[i * 4 + 2] = t.z; cs[i * 4 + 3] = t.w;
    }

#pragma unroll
    for (int j = 0; j < 8; ++j) {        // g2 outputs
        const float* wr = Wt2 + (wv * 8 + j) * 96;
        float a = wr[16];
#pragma unroll
        for (int f = 0; f < 16; ++f) a = fmaf(wr[f], pr[64 + f], a);
        val[lane][wv * 8 + j] = a > 0.f ? a : 0.f;
    }
#pragma unroll
    for (int j = 0; j < 8; ++j) {        // c2 outputs
        const float* wr = Wt2 + (32 + wv * 8 + j) * 96;
        float a = wr[80];
#pragma unroll
        for (int f = 0; f < 64; ++f) a = fmaf(wr[f], pr[f], a);
#pragma unroll
        for (int f = 0; f < 16; ++f) a = fmaf(wr[64 + f], cs[f], a);
        val[lane][32 + wv * 8 + j] = a > 0.f ? a : 0.f;
    }
    __syncthreads();

    // pooling: thread = (quarter q, channel c); 16 nodes per quarter
    int c = threadIdx.x & 63, q = threadIdx.x >> 6;
    int base = q * 16;
    float acc = 0.f;
    int curg = -1;
    for (int n = 0; n < 16; ++n) {
        int nd = tile * 64 + base + n;
        if (nd >= N_NODES) break;
        int gsg = sseg[base + n];
        if (gsg != curg) {
            if (curg >= 0) atomicAdd(&pool[curg * 64 + c], acc);
            acc = 0.f;
            curg = gsg;
        }
        acc += val[base + n][c];
    }
    if (curg >= 0) atomicAdd(&pool[curg * 64 + c], acc);
}

// ---------------------------------------------------------------------------
// K_head: 4 graphs per block (64 threads each = one wave per graph).
// Reads pool[G,64] (131 KB total) -> fused MLP head -> sigmoid.
// ---------------------------------------------------------------------------
__global__ __launch_bounds__(256) void k_head(
    const float* __restrict__ pool,
    const float* __restrict__ Wd1, const float* __restrict__ bd1,
    const float* __restrict__ Wd2, const float* __restrict__ bd2,
    const float* __restrict__ Wo,  const float* __restrict__ bo,
    float* __restrict__ out)
{
    __shared__ float pl[4][64];
    __shared__ float h1s[4][16];
    __shared__ float h2s[4][8];
    int q = threadIdx.x >> 6, t = threadIdx.x & 63;
    int g = blockIdx.x * 4 + q;
    pl[q][t] = pool[g * 64 + t];
    __syncthreads();
    if (t < 16) {
        float a = bd1[t];
        for (int k = 0; k < 64; ++k) a += pl[q][k] * Wd1[k * 16 + t];
        h1s[q][t] = a > 0.f ? a : 0.f;
    }
    __syncthreads();
    if (t < 8) {
        float a = bd2[t];
        for (int k = 0; k < 16; ++k) a += h1s[q][k] * Wd2[k * 8 + t];
        h2s[q][t] = a > 0.f ? a : 0.f;
    }
    __syncthreads();
    if (t == 0) {
        float a = bo[0];
        for (int k = 0; k < 8; ++k) a += h2s[q][k] * Wo[k];
        out[g] = 1.f / (1.f + expf(-a));
    }
}

// ---------------------------------------------------------------------------
// Workspace layout (~46 MB):
//   edata E*float4 | PQ1 N*56 | g1c1 N*32 | PQ2 N*80 | Wt1 2048 | Wt2 6144
//   rs[N] | pool[G*64] | bsum[256] | ecol[E]
//   (rs and pool contiguous -> single memset zeroes both)
// ---------------------------------------------------------------------------
extern "C" void kernel_launch(void* const* d_in, const int* in_sizes, int n_in,
                              void* d_out, int out_size, void* d_ws, size_t ws_size,
                              hipStream_t stream)
{
    const float* x      = (const float*)d_in[0];
    const float* a_vals = (const float*)d_in[1];
    const float* efeat  = (const float*)d_in[2];
    const int*   ei     = (const int*)d_in[3];
    const int*   seg    = (const int*)d_in[4];
    const float* Wg1    = (const float*)d_in[5];
    const float* bg1    = (const float*)d_in[6];
    const float* Wg2    = (const float*)d_in[7];
    const float* bg2    = (const float*)d_in[8];
    const float* We1    = (const float*)d_in[9];
    const float* be1    = (const float*)d_in[10];
    const float* root1  = (const float*)d_in[11];
    const float* bias1  = (const float*)d_in[12];
    const float* We2    = (const float*)d_in[13];
    const float* be2    = (const float*)d_in[14];
    const float* root2  = (const float*)d_in[15];
    const float* bias2  = (const float*)d_in[16];
    const float* Wd1    = (const float*)d_in[17];
    const float* bd1    = (const float*)d_in[18];
    const float* Wd2    = (const float*)d_in[19];
    const float* bd2    = (const float*)d_in[20];
    const float* Wo     = (const float*)d_in[21];
    const float* bo     = (const float*)d_in[22];

    float4* edata = (float4*)d_ws;
    float*  PQ1  = (float*)(edata + N_EDGES);
    float*  g1c1 = PQ1 + (size_t)N_NODES * PQ1_STRIDE;
    float*  PQ2  = g1c1 + (size_t)N_NODES * 32;
    float*  Wt1  = PQ2 + (size_t)N_NODES * 80;
    float*  Wt2  = Wt1 + 32 * 64;
    int*    rs   = (int*)(Wt2 + 64 * 96);
    float*  pool = (float*)(rs + N_NODES);
    int*    bsum = (int*)(pool + (size_t)G_DIM * 64);
    int*    ecol = bsum + 256;
    float*  out  = (float*)d_out;

    // zero rs (degree counters) and pool (atomic accumulators) in one shot
    hipMemsetAsync(rs, 0, sizeof(int) * (N_NODES + G_DIM * 64), stream);

    // CSR build (+ weight transpose folded into the 1-block scan_b)
    k_deg    <<<NB_EDGE, 256, 0, stream>>>(ei, rs);
    k_scan_a <<<NB_SCAN, 256, 0, stream>>>(rs, bsum);
    k_scan_b <<<1, 256, 0, stream>>>(bsum, Wg1, bg1, We1, be1, root1, bias1,
                                     Wg2, bg2, We2, be2, root2, bias2, Wt1, Wt2);
    k_fill   <<<NB_EDGE, 256, 0, stream>>>(ei, a_vals, efeat, rs, bsum, ecol, edata);

    // Layer 1: weight-free edge reduction + SGPR-weight transform
    k_edge1<<<N_NODES * 16 / 256, 256, 0, stream>>>(x, rs, bsum, ecol, edata, PQ1);
    k_tf1  <<<NB_TILE, 256, 0, stream>>>(PQ1, x, Wt1, g1c1);

    // Layer 2: edge reduction + transform fused with per-graph pooling
    k_edge2<<<N_NODES * 16 / 256, 256, 0, stream>>>(g1c1, rs, bsum, ecol, edata, PQ2);
    k_tf2pool<<<NB_TILE, 256, 0, stream>>>(PQ2, g1c1, seg, Wt2, pool);

    // MLP head
    k_head<<<G_DIM / 4, 256, 0, stream>>>(pool, Wd1, bd1, Wd2, bd2, Wo, bo, out);
}

// Round 5
// 190.060 us; speedup vs baseline: 1.2911x; 1.0230x over previous
//
#include <hip/hip_runtime.h>
#include <math.h>

#define N_NODES 60000
#define N_EDGES 240000
#define F_INQ 10
#define G_DIM 512
#define NB_SCAN ((N_NODES + 255) / 256)   // 235
#define NB_EDGE ((N_EDGES + 255) / 256)   // 938
#define NB_TILE ((N_NODES + 63) / 64)     // 938 64-node tiles
#define NB_E1  ((N_NODES * F_INQ + 255) / 256)  // 2344 (edge1 packed threads)
#define PQ1_STRIDE 56                     // 50 used, padded to 224B (16B-aligned rows)

// ===========================================================================
// CSR build: deg (+rank record) -> block scan -> block-sum scan (+ weight
// transpose) -> fill (atomic-free, also emits rowptr[N+1]).
// ===========================================================================
__global__ __launch_bounds__(256) void k_deg(
    const int* __restrict__ ei, int* __restrict__ rs, int* __restrict__ eslot)
{
    int e = blockIdx.x * 256 + threadIdx.x;
    if (e < N_EDGES) eslot[e] = atomicAdd(&rs[ei[e]], 1);
}

__global__ __launch_bounds__(256) void k_scan_a(
    int* __restrict__ rs, int* __restrict__ bsum)
{
    __shared__ int s[256];
    int i = blockIdx.x * 256 + threadIdx.x;
    int v = (i < N_NODES) ? rs[i] : 0;
    s[threadIdx.x] = v;
    __syncthreads();
    for (int off = 1; off < 256; off <<= 1) {
        int t = (threadIdx.x >= off) ? s[threadIdx.x - off] : 0;
        __syncthreads();
        s[threadIdx.x] += t;
        __syncthreads();
    }
    if (i < N_NODES) rs[i] = s[threadIdx.x] - v;  // block-local exclusive
    if (threadIdx.x == 255) bsum[blockIdx.x] = s[255];
}

// ---------------------------------------------------------------------------
// k_scan_b + weight transpose (1 block; transpose is independent filler work).
// Wt1[32][64]: rows 0..15  = g1 out o: [0..9]=Wg1[f][o], [10]=bg1[o]
//              rows 16..31 = c1 out o: [0..9]=be1 col, [10..19]=We1_0,
//                [20..29]=We1_1, [30..39]=We1_2, [40..49]=root1, [50]=bias1[o]
// Wt2[64][96]: rows 0..31  = g2 out o: [0..15]=Wg2[f][o], [16]=bg2[o]
//              rows 32..63 = c2 out o: [0..15]=be2 col, [16..31]=We2_0,
//                [32..47]=We2_1, [48..63]=We2_2, [64..79]=root2, [80]=bias2[o]
// ---------------------------------------------------------------------------
__global__ __launch_bounds__(256) void k_scan_b(
    int* __restrict__ bsum,
    const float* __restrict__ Wg1, const float* __restrict__ bg1,
    const float* __restrict__ We1, const float* __restrict__ be1,
    const float* __restrict__ root1, const float* __restrict__ bias1,
    const float* __restrict__ Wg2, const float* __restrict__ bg2,
    const float* __restrict__ We2, const float* __restrict__ be2,
    const float* __restrict__ root2, const float* __restrict__ bias2,
    float* __restrict__ Wt1, float* __restrict__ Wt2)
{
    __shared__ int s[256];
    int v = (threadIdx.x < NB_SCAN) ? bsum[threadIdx.x] : 0;
    s[threadIdx.x] = v;
    __syncthreads();
    for (int off = 1; off < 256; off <<= 1) {
        int t = (threadIdx.x >= off) ? s[threadIdx.x - off] : 0;
        __syncthreads();
        s[threadIdx.x] += t;
        __syncthreads();
    }
    if (threadIdx.x < NB_SCAN) bsum[threadIdx.x] = s[threadIdx.x] - v;  // exclusive

    // ---- weight transposes (no sync needed; independent of scan) ----
    for (int i = threadIdx.x; i < 16 * 11; i += 256) {
        int o = i / 11, f = i - o * 11;
        Wt1[o * 64 + f] = (f < 10) ? Wg1[f * 16 + o] : bg1[o];
    }
    for (int i = threadIdx.x; i < 16 * 51; i += 256) {
        int o = i / 51, f = i - o * 51;
        float w;
        if      (f < 10) w = be1[f * 16 + o];
        else if (f < 20) w = We1[(f - 10) * 16 + o];
        else if (f < 30) w = We1[160 + (f - 20) * 16 + o];
        else if (f < 40) w = We1[320 + (f - 30) * 16 + o];
        else if (f < 50) w = root1[(f - 40) * 16 + o];
        else             w = bias1[o];
        Wt1[(16 + o) * 64 + f] = w;
    }
    for (int i = threadIdx.x; i < 32 * 17; i += 256) {
        int o = i / 17, f = i - o * 17;
        Wt2[o * 96 + f] = (f < 16) ? Wg2[f * 32 + o] : bg2[o];
    }
    for (int i = threadIdx.x; i < 32 * 81; i += 256) {
        int o = i / 81, f = i - o * 81;
        float w;
        if      (f < 16) w = be2[f * 32 + o];
        else if (f < 32) w = We2[(f - 16) * 32 + o];
        else if (f < 48) w = We2[512 + (f - 32) * 32 + o];
        else if (f < 64) w = We2[1024 + (f - 48) * 32 + o];
        else if (f < 80) w = root2[(f - 64) * 32 + o];
        else             w = bias2[o];
        Wt2[(32 + o) * 96 + f] = w;
    }
}

// ---------------------------------------------------------------------------
// k_fill: atomic-free (slot = prefix[row] + eslot[e]); also emits
// rowptr[i] = global start of node i, rowptr[N] = E.
// ---------------------------------------------------------------------------
__global__ __launch_bounds__(256) void k_fill(
    const int* __restrict__ ei, const float* __restrict__ a_vals,
    const float* __restrict__ efeat, const int* __restrict__ eslot,
    const int* __restrict__ rs, const int* __restrict__ bsum,
    int* __restrict__ ecol, float4* __restrict__ edata,
    int* __restrict__ rowptr)
{
    int e = blockIdx.x * 256 + threadIdx.x;
    if (e <= N_NODES) {
        rowptr[e] = (e == N_NODES) ? N_EDGES : rs[e] + bsum[e >> 8];
    }
    if (e >= N_EDGES) return;
    int row = ei[e];
    int slot = rs[row] + bsum[row >> 8] + eslot[e];
    ecol[slot] = ei[N_EDGES + e];
    edata[slot] = make_float4(a_vals[e], efeat[e * 3], efeat[e * 3 + 1], efeat[e * 3 + 2]);
}

// ---------------------------------------------------------------------------
// K_edge1: weight-free CSR reduction, layer 1. Zero LDS, max occupancy.
// PACKED lanes: thread = node*10 + f (100% lane utilization; 600K threads).
// 2-way unroll keeps two gather chains in flight. PQ1[n,56] = [P0|P1|P2|P3|Q].
// ---------------------------------------------------------------------------
__global__ __launch_bounds__(256) void k_edge1(
    const float* __restrict__ x,
    const int* __restrict__ rowptr,
    const int* __restrict__ ecol, const float4* __restrict__ edata,
    float* __restrict__ PQ1)
{
    int idx = blockIdx.x * 256 + threadIdx.x;
    if (idx >= N_NODES * F_INQ) return;
    int node = idx / F_INQ;
    int f = idx - node * F_INQ;
    int start = rowptr[node], end = rowptr[node + 1];
    float p0 = 0.f, p1 = 0.f, p2 = 0.f, p3 = 0.f, q = 0.f;
    int k = start;
    for (; k + 2 <= end; k += 2) {
        int c0 = ecol[k], c1 = ecol[k + 1];
        float4 e0 = edata[k], e1 = edata[k + 1];
        float x0 = x[c0 * F_INQ + f];
        float x1 = x[c1 * F_INQ + f];
        p0 += x0;        p0 += x1;
        p1 += e0.y * x0; p1 += e1.y * x1;
        p2 += e0.z * x0; p2 += e1.z * x1;
        p3 += e0.w * x0; p3 += e1.w * x1;
        q  += e0.x * x0; q  += e1.x * x1;
    }
    if (k < end) {
        int c0 = ecol[k];
        float4 e0 = edata[k];
        float x0 = x[c0 * F_INQ + f];
        p0 += x0;
        p1 += e0.y * x0;
        p2 += e0.z * x0;
        p3 += e0.w * x0;
        q  += e0.x * x0;
    }
    float* P = PQ1 + (size_t)node * PQ1_STRIDE;
    P[f]      = p0;
    P[10 + f] = p1;
    P[20 + f] = p2;
    P[30 + f] = p3;
    P[40 + f] = q;
}

// ---------------------------------------------------------------------------
// K_tf1: transform 1, SGPR-weight formulation. Lane = node (64-node tile),
// wave = output-group; weight rows wave-uniform -> SGPRs -> v_fmac.
// Output gc[n,32] INTERLEAVED: gc[n][2f]=g1[f], gc[n][2f+1]=c1[f]
// (so edge2 fetches both with ONE dwordx2 per col per lane).
// ---------------------------------------------------------------------------
__global__ __launch_bounds__(256) void k_tf1(
    const float* __restrict__ PQ1,
    const float* __restrict__ x,
    const float* __restrict__ Wt1,
    float* __restrict__ gc)
{
    __shared__ float val[64][33];
    int tile = blockIdx.x;
    int lane = threadIdx.x & 63;
    int wv = __builtin_amdgcn_readfirstlane(threadIdx.x >> 6);   // 0..3
    int node = tile * 64 + lane;
    int nclamp = node < N_NODES ? node : N_NODES - 1;

    float pr[52];
    const float4* P4 = (const float4*)(PQ1 + (size_t)nclamp * PQ1_STRIDE);
#pragma unroll
    for (int i = 0; i < 13; ++i) {
        float4 t = P4[i];
        pr[i * 4] = t.x; pr[i * 4 + 1] = t.y; pr[i * 4 + 2] = t.z; pr[i * 4 + 3] = t.w;
    }
    float xs[10];
    const float2* X2 = (const float2*)(x + (size_t)nclamp * F_INQ);
#pragma unroll
    for (int i = 0; i < 5; ++i) {
        float2 t = X2[i];
        xs[i * 2] = t.x; xs[i * 2 + 1] = t.y;
    }

#pragma unroll
    for (int j = 0; j < 4; ++j) {        // g1 outputs -> even slots
        const float* wr = Wt1 + (wv * 4 + j) * 64;
        float a = wr[10];
#pragma unroll
        for (int f = 0; f < 10; ++f) a = fmaf(wr[f], pr[40 + f], a);
        val[lane][(wv * 4 + j) * 2] = a > 0.f ? a : 0.f;
    }
#pragma unroll
    for (int j = 0; j < 4; ++j) {        // c1 outputs -> odd slots
        const float* wr = Wt1 + (16 + wv * 4 + j) * 64;
        float a = wr[50];
#pragma unroll
        for (int f = 0; f < 40; ++f) a = fmaf(wr[f], pr[f], a);
#pragma unroll
        for (int f = 0; f < 10; ++f) a = fmaf(wr[40 + f], xs[f], a);
        val[lane][(wv * 4 + j) * 2 + 1] = a > 0.f ? a : 0.f;
    }
    __syncthreads();

    float4* G4 = (float4*)(gc + (size_t)tile * 64 * 32);
#pragma unroll
    for (int k = 0; k < 2; ++k) {
        int fi4 = k * 256 + threadIdx.x;
        int n = fi4 >> 3, o4 = (fi4 & 7) * 4;
        if (tile * 64 + n < N_NODES)
            G4[fi4] = make_float4(val[n][o4], val[n][o4 + 1], val[n][o4 + 2], val[n][o4 + 3]);
    }
}

// ---------------------------------------------------------------------------
// K_edge2: weight-free CSR reduction, layer 2. Zero LDS, max occupancy.
// Lane = (node, f<16). Interleaved gc -> ONE float2 load per col per lane
// gives both g1 (.x) and c1 (.y). PQ2[n,80] = [P0|P1|P2|P3|Q].
// ---------------------------------------------------------------------------
__global__ __launch_bounds__(256) void k_edge2(
    const float* __restrict__ gc,
    const int* __restrict__ rowptr,
    const int* __restrict__ ecol, const float4* __restrict__ edata,
    float* __restrict__ PQ2)
{
    int idx = blockIdx.x * 256 + threadIdx.x;   // 3750 blocks exact
    int node = idx >> 4, f = idx & 15;
    int start = rowptr[node], end = rowptr[node + 1];
    const float2* GC2 = (const float2*)gc;
    float p0 = 0.f, p1 = 0.f, p2 = 0.f, p3 = 0.f, q = 0.f;
    int k = start;
    for (; k + 2 <= end; k += 2) {
        int c0 = ecol[k], c1 = ecol[k + 1];
        float4 e0 = edata[k], e1 = edata[k + 1];
        float2 t0 = GC2[c0 * 16 + f];
        float2 t1 = GC2[c1 * 16 + f];
        p0 += t0.y;        p0 += t1.y;
        p1 += e0.y * t0.y; p1 += e1.y * t1.y;
        p2 += e0.z * t0.y; p2 += e1.z * t1.y;
        p3 += e0.w * t0.y; p3 += e1.w * t1.y;
        q  += e0.x * t0.x; q  += e1.x * t1.x;
    }
    if (k < end) {
        int c0 = ecol[k];
        float4 e0 = edata[k];
        float2 t0 = GC2[c0 * 16 + f];
        p0 += t0.y;
        p1 += e0.y * t0.y;
        p2 += e0.z * t0.y;
        p3 += e0.w * t0.y;
        q  += e0.x * t0.x;
    }
    float* P = PQ2 + (size_t)node * 80;
    P[f]      = p0;
    P[16 + f] = p1;
    P[32 + f] = p2;
    P[48 + f] = p3;
    P[64 + f] = q;
}

// ---------------------------------------------------------------------------
// K_tf2pool: transform 2 + per-graph pooling, SGPR-weight formulation.
// Lane = node (64-node tile), wave = output-group (8 g2 + 8 c2 outputs).
// c1_self extracted from interleaved gc (odd slots). val[64] block layout
// [g2(32)|c2(32)] -> pool[G,64] via sorted-seg run-detect atomics.
// ---------------------------------------------------------------------------
__global__ __launch_bounds__(256) void k_tf2pool(
    const float* __restrict__ PQ2,
    const float* __restrict__ gc,
    const int* __restrict__ seg,
    const float* __restrict__ Wt2,
    float* __restrict__ pool)
{
    __shared__ float val[64][65];
    __shared__ int sseg[64];
    int tile = blockIdx.x;
    int lane = threadIdx.x & 63;
    int wv = __builtin_amdgcn_readfirstlane(threadIdx.x >> 6);   // 0..3
    int node = tile * 64 + lane;
    int nclamp = node < N_NODES ? node : N_NODES - 1;

    if (threadIdx.x < 64) {
        int nd = tile * 64 + threadIdx.x;
        sseg[threadIdx.x] = (nd < N_NODES) ? seg[nd] : -1;
    }

    float pr[80];
    const float4* P4 = (const float4*)(PQ2 + (size_t)nclamp * 80);
#pragma unroll
    for (int i = 0; i < 20; ++i) {
        float4 t = P4[i];
        pr[i * 4] = t.x; pr[i * 4 + 1] = t.y; pr[i * 4 + 2] = t.z; pr[i * 4 + 3] = t.w;
    }
    float cs[16];
    const float4* C4 = (const float4*)(gc + (size_t)nclamp * 32);
#pragma unroll
    for (int i = 0; i < 8; ++i) {        // (g,c,g,c) -> take odd (c1)
        float4 t = C4[i];
        cs[i * 2] = t.y; cs[i * 2 + 1] = t.w;
    }

#pragma unroll
    for (int j = 0; j < 8; ++j) {        // g2 outputs
        const float* wr = Wt2 + (wv * 8 + j) * 96;
        float a = wr[16];
#pragma unroll
        for (int f = 0; f < 16; ++f) a = fmaf(wr[f], pr[64 + f], a);
        val[lane][wv * 8 + j] = a > 0.f ? a : 0.f;
    }
#pragma unroll
    for (int j = 0; j < 8; ++j) {        // c2 outputs
        const float* wr = Wt2 + (32 + wv * 8 + j) * 96;
        float a = wr[80];
#pragma unroll
        for (int f = 0; f < 64; ++f) a = fmaf(wr[f], pr[f], a);
#pragma unroll
        for (int f = 0; f < 16; ++f) a = fmaf(wr[64 + f], cs[f], a);
        val[lane][32 + wv * 8 + j] = a > 0.f ? a : 0.f;
    }
    __syncthreads();

    // pooling: thread = (quarter q, channel c); 16 nodes per quarter
    int c = threadIdx.x & 63, q = threadIdx.x >> 6;
    int base = q * 16;
    float acc = 0.f;
    int curg = -1;
    for (int n = 0; n < 16; ++n) {
        int nd = tile * 64 + base + n;
        if (nd >= N_NODES) break;
        int gsg = sseg[base + n];
        if (gsg != curg) {
            if (curg >= 0) atomicAdd(&pool[curg * 64 + c], acc);
            acc = 0.f;
            curg = gsg;
        }
        acc += val[base + n][c];
    }
    if (curg >= 0) atomicAdd(&pool[curg * 64 + c], acc);
}

// ---------------------------------------------------------------------------
// K_head: 4 graphs per block (64 threads each = one wave per graph).
// Reads pool[G,64] (131 KB total) -> fused MLP head -> sigmoid.
// ---------------------------------------------------------------------------
__global__ __launch_bounds__(256) void k_head(
    const float* __restrict__ pool,
    const float* __restrict__ Wd1, const float* __restrict__ bd1,
    const float* __restrict__ Wd2, const float* __restrict__ bd2,
    const float* __restrict__ Wo,  const float* __restrict__ bo,
    float* __restrict__ out)
{
    __shared__ float pl[4][64];
    __shared__ float h1s[4][16];
    __shared__ float h2s[4][8];
    int q = threadIdx.x >> 6, t = threadIdx.x & 63;
    int g = blockIdx.x * 4 + q;
    pl[q][t] = pool[g * 64 + t];
    __syncthreads();
    if (t < 16) {
        float a = bd1[t];
        for (int k = 0; k < 64; ++k) a += pl[q][k] * Wd1[k * 16 + t];
        h1s[q][t] = a > 0.f ? a : 0.f;
    }
    __syncthreads();
    if (t < 8) {
        float a = bd2[t];
        for (int k = 0; k < 16; ++k) a += h1s[q][k] * Wd2[k * 8 + t];
        h2s[q][t] = a > 0.f ? a : 0.f;
    }
    __syncthreads();
    if (t == 0) {
        float a = bo[0];
        for (int k = 0; k < 8; ++k) a += h2s[q][k] * Wo[k];
        out[g] = 1.f / (1.f + expf(-a));
    }
}

// ---------------------------------------------------------------------------
// Workspace layout (~48 MB):
//   edata E*float4 | PQ1 N*56 | gc N*32 | PQ2 N*80 | Wt1 2048 | Wt2 6144
//   rs[N] | pool[G*64] | bsum[256] | ecol[E] | eslot[E] | rowptr[N+1]
//   (rs and pool contiguous -> single memset zeroes both)
// ---------------------------------------------------------------------------
extern "C" void kernel_launch(void* const* d_in, const int* in_sizes, int n_in,
                              void* d_out, int out_size, void* d_ws, size_t ws_size,
                              hipStream_t stream)
{
    const float* x      = (const float*)d_in[0];
    const float* a_vals = (const float*)d_in[1];
    const float* efeat  = (const float*)d_in[2];
    const int*   ei     = (const int*)d_in[3];
    const int*   seg    = (const int*)d_in[4];
    const float* Wg1    = (const float*)d_in[5];
    const float* bg1    = (const float*)d_in[6];
    const float* Wg2    = (const float*)d_in[7];
    const float* bg2    = (const float*)d_in[8];
    const float* We1    = (const float*)d_in[9];
    const float* be1    = (const float*)d_in[10];
    const float* root1  = (const float*)d_in[11];
    const float* bias1  = (const float*)d_in[12];
    const float* We2    = (const float*)d_in[13];
    const float* be2    = (const float*)d_in[14];
    const float* root2  = (const float*)d_in[15];
    const float* bias2  = (const float*)d_in[16];
    const float* Wd1    = (const float*)d_in[17];
    const float* bd1    = (const float*)d_in[18];
    const float* Wd2    = (const float*)d_in[19];
    const float* bd2    = (const float*)d_in[20];
    const float* Wo     = (const float*)d_in[21];
    const float* bo     = (const float*)d_in[22];

    float4* edata = (float4*)d_ws;
    float*  PQ1  = (float*)(edata + N_EDGES);
    float*  gc   = PQ1 + (size_t)N_NODES * PQ1_STRIDE;
    float*  PQ2  = gc + (size_t)N_NODES * 32;
    float*  Wt1  = PQ2 + (size_t)N_NODES * 80;
    float*  Wt2  = Wt1 + 32 * 64;
    int*    rs   = (int*)(Wt2 + 64 * 96);
    float*  pool = (float*)(rs + N_NODES);
    int*    bsum = (int*)(pool + (size_t)G_DIM * 64);
    int*    ecol = bsum + 256;
    int*    eslot = ecol + N_EDGES;
    int*    rowptr = eslot + N_EDGES;
    float*  out  = (float*)d_out;

    // zero rs (degree counters) and pool (atomic accumulators) in one shot
    hipMemsetAsync(rs, 0, sizeof(int) * (N_NODES + G_DIM * 64), stream);

    // CSR build (+ weight transpose folded into the 1-block scan_b)
    k_deg    <<<NB_EDGE, 256, 0, stream>>>(ei, rs, eslot);
    k_scan_a <<<NB_SCAN, 256, 0, stream>>>(rs, bsum);
    k_scan_b <<<1, 256, 0, stream>>>(bsum, Wg1, bg1, We1, be1, root1, bias1,
                                     Wg2, bg2, We2, be2, root2, bias2, Wt1, Wt2);
    k_fill   <<<NB_EDGE, 256, 0, stream>>>(ei, a_vals, efeat, eslot, rs, bsum,
                                           ecol, edata, rowptr);

    // Layer 1: packed edge reduction + SGPR-weight transform
    k_edge1<<<NB_E1, 256, 0, stream>>>(x, rowptr, ecol, edata, PQ1);
    k_tf1  <<<NB_TILE, 256, 0, stream>>>(PQ1, x, Wt1, gc);

    // Layer 2: edge reduction (1-load gather) + transform fused with pooling
    k_edge2<<<N_NODES * 16 / 256, 256, 0, stream>>>(gc, rowptr, ecol, edata, PQ2);
    k_tf2pool<<<NB_TILE, 256, 0, stream>>>(PQ2, gc, seg, Wt2, pool);

    // MLP head
    k_head<<<G_DIM / 4, 256, 0, stream>>>(pool, Wd1, bd1, Wd2, bd2, Wo, bo, out);
}